// Round 8
// baseline (277.898 us; speedup 1.0000x reference)
//
#include <hip/hip_runtime.h>
#include <stdint.h>

typedef unsigned short u16;
typedef __bf16 bf16x8 __attribute__((ext_vector_type(8)));
typedef float f32x4 __attribute__((ext_vector_type(4)));

__device__ __forceinline__ float bf2f(u16 v){ return __uint_as_float(((unsigned)v)<<16); }
__device__ __forceinline__ u16 f2bf(float f){
  unsigned u = __float_as_uint(f);
  unsigned r = (u + 0x7FFFu + ((u>>16)&1u)) >> 16;
  return (u16)r;
}
__device__ __forceinline__ float fexp2(float x){
#if __has_builtin(__builtin_amdgcn_exp2f)
  return __builtin_amdgcn_exp2f(x);
#else
  return exp2f(x);
#endif
}

// ---------------------------------------------------------------------------
// Prep: weight transpose fp32->bf16 [n][k] (blocks 0-639; blocks 0-63 also
// zero stats) + x fp32->bf16 (blocks 640-2687). W1 column-interleaved.
// ---------------------------------------------------------------------------
__global__ void prep_kernel(const float* __restrict__ x_, u16* __restrict__ xb,
                            const float* __restrict__ Wq, const float* __restrict__ Wk,
                            const float* __restrict__ Wv, const float* __restrict__ Wo,
                            const float* __restrict__ W1, const float* __restrict__ W2,
                            u16* __restrict__ wqkvT, u16* __restrict__ woT,
                            u16* __restrict__ w1T, u16* __restrict__ w2T,
                            float* __restrict__ SS)
{
  int bid = blockIdx.x;
  int t = threadIdx.x;
  if (bid >= 640) {
    int idx = ((bid - 640) * 256 + t) * 8;
    float4 a0 = *(const float4*)(x_ + idx);
    float4 a1 = *(const float4*)(x_ + idx + 4);
    union { u16 u[8]; uint4 v; } pk;
    pk.u[0] = f2bf(a0.x); pk.u[1] = f2bf(a0.y); pk.u[2] = f2bf(a0.z); pk.u[3] = f2bf(a0.w);
    pk.u[4] = f2bf(a1.x); pk.u[5] = f2bf(a1.y); pk.u[6] = f2bf(a1.z); pk.u[7] = f2bf(a1.w);
    *(uint4*)(xb + idx) = pk.v;
    return;
  }
  if (bid < 64) SS[bid * 256 + t] = 0.f;
  __shared__ u16 tile[32][33];
  const float* in; u16* out; int K, N, t2; bool glu = false;
  if (bid < 64)       { in = Wq; out = wqkvT;           K = 256; N = 256;  t2 = bid; }
  else if (bid < 128) { in = Wk; out = wqkvT + 65536;   K = 256; N = 256;  t2 = bid - 64; }
  else if (bid < 192) { in = Wv; out = wqkvT + 131072;  K = 256; N = 256;  t2 = bid - 128; }
  else if (bid < 256) { in = Wo; out = woT;             K = 256; N = 256;  t2 = bid - 192; }
  else if (bid < 512) { in = W1; out = w1T;             K = 256; N = 1024; t2 = bid - 256; glu = true; }
  else                { in = W2; out = w2T;             K = 512; N = 256;  t2 = bid - 512; }
  int ntn = N >> 5;
  int k0 = (t2 / ntn) * 32, n0 = (t2 % ntn) * 32;
  #pragma unroll
  for (int p = 0; p < 4; ++p) {
    int u = t + p * 256; int r = u >> 5, c = u & 31;
    tile[r][c] = f2bf(in[(size_t)(k0 + r) * N + n0 + c]);
  }
  __syncthreads();
  #pragma unroll
  for (int p = 0; p < 4; ++p) {
    int u = t + p * 256; int r = u >> 5, c = u & 31;
    int q = n0 + r;
    int row = glu ? (q < 512 ? 2 * q : 2 * (q - 512) + 1) : q;
    out[(size_t)row * K + k0 + c] = tile[c][r];
  }
}

// ---------------------------------------------------------------------------
// GEMM v2: 128xTN tile, BK=64, software-pipelined staging (prefetch next
// K-slab into VGPRs during MFMA), LDS-transpose vectorized epilogues.
// ---------------------------------------------------------------------------
enum { MODE_QKV = 0, MODE_Y_RES = 1, MODE_GLU = 2 };

template<int MODE, int TN, int RESN, int STATS, int NORMA>
__launch_bounds__(256, 3)
__global__ void gemm_kernel(const u16* __restrict__ A, const u16* __restrict__ BT,
                            int M, int N, int K,
                            const float* __restrict__ bias, const u16* __restrict__ resp,
                            u16* __restrict__ outB,
                            float* __restrict__ ssum, float* __restrict__ ssq,
                            const float* __restrict__ nsum, const float* __restrict__ nsq,
                            const float* __restrict__ ngam, const float* __restrict__ nbet)
{
  constexpr int NJ = TN / 32;               // 4 (TN=128) / 2 (TN=64)
  constexpr int AU = 4;                     // A staging units/thread (8 elems each)
  constexpr int BU = TN / 32;               // B staging units/thread
  constexpr int STG = (128 + TN) * 72;      // staging u16
  constexpr int TSZ = 128 * (TN + 8);       // transpose u16
  __shared__ u16 LDSbuf[STG > TSZ ? STG : TSZ];
  u16* As = LDSbuf;
  u16* Bs = LDSbuf + 128 * 72;
  __shared__ float scA[256], sfA[256];
  const int t = threadIdx.x;
  const int m0 = blockIdx.x * 128;
  const int n0 = blockIdx.y * TN;
  const int lane = t & 63;
  const int w = t >> 6;
  const int wm = (w >> 1) * 64;
  const int wn = (w & 1) * (NJ * 16);
  const int fr = lane & 15;
  const int fg = lane >> 4;
  const int bIdx = m0 >> 10;
  const float inv1024 = 1.f / 1024.f;

  if (NORMA) {
    int e = t;
    float mean = nsum[bIdx * 256 + e] * inv1024;
    float var = nsq[bIdx * 256 + e] * inv1024 - mean * mean;
    float rstd = rsqrtf(var + 1e-5f);
    float sc = rstd * ngam[e];
    scA[e] = sc;
    sfA[e] = nbet[e] - mean * sc;
  }

  f32x4 acc[4][NJ];
  #pragma unroll
  for (int i = 0; i < 4; ++i)
    #pragma unroll
    for (int j = 0; j < NJ; ++j)
      acc[i][j] = (f32x4){0.f, 0.f, 0.f, 0.f};

  const int arow = t >> 3, acb = t & 7;          // A unit base (g = t + u*256)
  uint4 ra[AU], rb[BU];
  // prefetch slab 0
  #pragma unroll
  for (int u = 0; u < AU; ++u)
    ra[u] = *(const uint4*)(A + (size_t)(m0 + arow + u * 32) * K + acb * 8);
  #pragma unroll
  for (int u = 0; u < BU; ++u)
    rb[u] = *(const uint4*)(BT + (size_t)(n0 + arow + u * 32) * K + acb * 8);

  const int NS = K >> 6;
  for (int s = 0; s < NS; ++s) {
    __syncthreads();
    #pragma unroll
    for (int u = 0; u < AU; ++u) {
      int row = arow + u * 32;
      if (NORMA) {
        union { u16 u[8]; uint4 v; } in, o;
        in.v = ra[u];
        int kb = s * 64 + acb * 8;
        const float* scp = scA + kb;
        const float* sfp = sfA + kb;
        #pragma unroll
        for (int q = 0; q < 8; ++q) o.u[q] = f2bf(bf2f(in.u[q]) * scp[q] + sfp[q]);
        *(uint4*)(As + row * 72 + acb * 8) = o.v;
      } else {
        *(uint4*)(As + row * 72 + acb * 8) = ra[u];
      }
    }
    #pragma unroll
    for (int u = 0; u < BU; ++u)
      *(uint4*)(Bs + (arow + u * 32) * 72 + acb * 8) = rb[u];
    __syncthreads();
    if (s + 1 < NS) {      // issue next slab's loads; land during MFMA below
      int k0 = (s + 1) * 64;
      #pragma unroll
      for (int u = 0; u < AU; ++u)
        ra[u] = *(const uint4*)(A + (size_t)(m0 + arow + u * 32) * K + k0 + acb * 8);
      #pragma unroll
      for (int u = 0; u < BU; ++u)
        rb[u] = *(const uint4*)(BT + (size_t)(n0 + arow + u * 32) * K + k0 + acb * 8);
    }
    #pragma unroll
    for (int kh = 0; kh < 2; ++kh) {
      bf16x8 af[4], bfr[NJ];
      #pragma unroll
      for (int i = 0; i < 4; ++i)
        af[i] = *(const bf16x8*)(As + (wm + i * 16 + fr) * 72 + kh * 32 + fg * 8);
      #pragma unroll
      for (int j = 0; j < NJ; ++j)
        bfr[j] = *(const bf16x8*)(Bs + (wn + j * 16 + fr) * 72 + kh * 32 + fg * 8);
      #pragma unroll
      for (int i = 0; i < 4; ++i)
        #pragma unroll
        for (int j = 0; j < NJ; ++j)
          acc[i][j] = __builtin_amdgcn_mfma_f32_16x16x32_bf16(af[i], bfr[j], acc[i][j], 0, 0, 0);
    }
  }

  // ---- epilogue: C-layout math -> LDS transpose -> vectorized stores ----
  __syncthreads();                // all waves done reading As/Bs
  u16* Ts = LDSbuf;               // [128][TN+8]
  constexpr int TP = TN + 8;
  #pragma unroll
  for (int j = 0; j < NJ; ++j) {
    int col = n0 + wn + j * 16 + fr;
    int lcol = wn + j * 16 + fr;
    float bv = 0.f;
    if (MODE == MODE_Y_RES) bv = bias[col];
    if (MODE == MODE_GLU)   bv = bias[(col >> 1) + ((col & 1) << 9)];
    float scj = 0.f, sfj = 0.f;
    if (RESN == 2) {
      float mean = nsum[bIdx * 256 + col] * inv1024;
      float var = nsq[bIdx * 256 + col] * inv1024 - mean * mean;
      float rstd = rsqrtf(var + 1e-5f);
      scj = rstd * ngam[col];
      sfj = nbet[col] - mean * scj;
    }
    float sj = 0.f, qj = 0.f;
    #pragma unroll
    for (int i = 0; i < 4; ++i) {
      #pragma unroll
      for (int r = 0; r < 4; ++r) {
        int lrow = wm + i * 16 + fg * 4 + r;
        float v = acc[i][j][r] + bv;
        if (MODE == MODE_Y_RES) {
          size_t idx = (size_t)(m0 + lrow) * N + col;
          float rv = bf2f(resp[idx]);
          if (RESN == 2) rv = rv * scj + sfj;
          v += rv;
          if (STATS) { sj += v; qj += v * v; }
        }
        Ts[lrow * TP + lcol] = f2bf(v);
      }
    }
    if (STATS) {
      sj += __shfl_xor(sj, 16); sj += __shfl_xor(sj, 32);
      qj += __shfl_xor(qj, 16); qj += __shfl_xor(qj, 32);
      if (fg == 0) {
        atomicAdd(&ssum[bIdx * 256 + col], sj);
        atomicAdd(&ssq[bIdx * 256 + col], qj);
      }
    }
  }
  __syncthreads();

  if (MODE == MODE_QKV) {
    // scatter [b][h][n][d] in 16-B segments: 128x128 tile = 16 col-octets
    #pragma unroll
    for (int p = 0; p < 8; ++p) {
      int g = t + p * 256;
      int lrow = g >> 4, oct = g & 15;
      int row = m0 + lrow;
      int col0 = n0 + oct * 8;
      int which = col0 >> 8, h = (col0 >> 4) & 15, dh = (col0 >> 3) & 1;
      int b = row >> 10, ns = row & 1023;
      uint4 v = *(const uint4*)(Ts + lrow * TP + oct * 8);
      *(uint4*)(outB + (size_t)which * 4194304 +
                (((size_t)(b * 16 + h) * 1024 + ns) * 16 + dh * 8)) = v;
    }
  } else if (MODE == MODE_Y_RES) {
    // plain row-major, 16-B segments: TN=64 -> 8 octets, 4 iters
    #pragma unroll
    for (int p = 0; p < TN / 16; ++p) {
      int g = t + p * 256;
      int lrow = g >> 3, oct = g & 7;
      uint4 v = *(const uint4*)(Ts + lrow * TP + oct * 8);
      *(uint4*)(outB + (size_t)(m0 + lrow) * N + n0 + oct * 8) = v;
    }
  } else {
    // GLU: pairs (even,odd)=(x,gate) -> 8 outputs per 16 raw cols
    #pragma unroll
    for (int p = 0; p < 4; ++p) {
      int g = t + p * 256;
      int lrow = g >> 3, grp = g & 7;
      union { u16 u[8]; uint4 v; } r0, r1, o;
      r0.v = *(const uint4*)(Ts + lrow * TP + grp * 16);
      r1.v = *(const uint4*)(Ts + lrow * TP + grp * 16 + 8);
      #pragma unroll
      for (int q = 0; q < 4; ++q) {
        float xv = bf2f(r0.u[2 * q]), gv = bf2f(r0.u[2 * q + 1]);
        o.u[q] = f2bf(xv * gv / (1.f + __expf(-gv)));
      }
      #pragma unroll
      for (int q = 0; q < 4; ++q) {
        float xv = bf2f(r1.u[2 * q]), gv = bf2f(r1.u[2 * q + 1]);
        o.u[4 + q] = f2bf(xv * gv / (1.f + __expf(-gv)));
      }
      *(uint4*)(outB + (size_t)(m0 + lrow) * (N >> 1) + (n0 >> 1) + grp * 8) = o.v;
    }
  }
}

// ---------------------------------------------------------------------------
// Attention v3 (unchanged from r7).
// ---------------------------------------------------------------------------
#define SCALE_L2 0.360673760222241f

__launch_bounds__(512, 4)
__global__ void attn_kernel(const u16* __restrict__ Q, const u16* __restrict__ Kg,
                            const u16* __restrict__ Vg, u16* __restrict__ attn)
{
  __shared__ u16 Ks[2][128 * 24];
  __shared__ u16 Vt[2][16 * 136];
  __shared__ u16 Pb[8][16 * 40];
  const int t = threadIdx.x;
  const int bh = blockIdx.x & 255;
  const int qg = blockIdx.x >> 8;
  const int b = bh >> 4, h = bh & 15;
  const size_t base = (size_t)bh * 16384;
  const int w = t >> 6, lane = t & 63;
  const int fr = lane & 15, fg = lane >> 4;
  u16* Pw = Pb[w];
  const int q0 = qg * 128 + w * 16;
  const f32x4 zero4 = (f32x4){0.f, 0.f, 0.f, 0.f};

  const int su = (t & 255) >> 1;
  const int sh = t & 1;
  const bool isK = t < 256;
  const int blk = su >> 5, ii = su & 31;
  const int kpos = blk * 32 + ((ii & 1) ? 16 + (ii >> 1) : (ii >> 1));

  bf16x8 qf = {};
  if (fg < 2) {
    union { u16 u[8]; uint4 v; bf16x8 f; } qt;
    qt.v = *(const uint4*)(Q + base + (size_t)(q0 + fr) * 16 + fg * 8);
    #pragma unroll
    for (int j = 0; j < 8; ++j) qt.u[j] = f2bf(bf2f(qt.u[j]) * SCALE_L2);
    qf = qt.f;
  }

  {
    uint4 pre = isK ? *(const uint4*)(Kg + base + (size_t)su * 16 + sh * 8)
                    : *(const uint4*)(Vg + base + (size_t)su * 16 + sh * 8);
    if (isK) {
      *(uint4*)(&Ks[0][kpos * 24 + sh * 8]) = pre;
    } else {
      union { u16 u[8]; uint4 v; } pk; pk.v = pre;
      #pragma unroll
      for (int j = 0; j < 8; ++j) Vt[0][(sh * 8 + j) * 136 + su] = pk.u[j];
    }
  }
  __syncthreads();

  f32x4 acco = zero4;
  float lsum[4] = {0.f, 0.f, 0.f, 0.f};

  for (int c = 0; c < 8; ++c) {
    uint4 nxt;
    if (c < 7) {
      const size_t off = base + (size_t)((c + 1) * 128 + su) * 16 + sh * 8;
      nxt = isK ? *(const uint4*)(Kg + off) : *(const uint4*)(Vg + off);
    }
    const u16* KsC = Ks[c & 1];
    const u16* VtC = Vt[c & 1];
    #pragma unroll
    for (int sub = 0; sub < 4; ++sub) {
      const int kb = sub * 32;
      bf16x8 kf0 = {}, kf1 = {};
      if (fg < 2) {
        kf0 = *(const bf16x8*)(KsC + (kb + fr) * 24 + fg * 8);
        kf1 = *(const bf16x8*)(KsC + (kb + 16 + fr) * 24 + fg * 8);
      }
      f32x4 s0 = __builtin_amdgcn_mfma_f32_16x16x32_bf16(qf, kf0, zero4, 0, 0, 0);
      f32x4 s1 = __builtin_amdgcn_mfma_f32_16x16x32_bf16(qf, kf1, zero4, 0, 0, 0);
      #pragma unroll
      for (int r = 0; r < 4; ++r) {
        float p0 = fexp2(s0[r]);
        float p1 = fexp2(s1[r]);
        lsum[r] += p0 + p1;
        *(unsigned*)(Pw + (fg * 4 + r) * 40 + 2 * fr) =
            __builtin_amdgcn_perm(__float_as_uint(p1), __float_as_uint(p0), 0x07060302u);
      }
      __asm__ volatile("s_waitcnt lgkmcnt(0)" ::: "memory");
      bf16x8 pf = *(const bf16x8*)(Pw + fr * 40 + fg * 8);
      bf16x8 vf = *(const bf16x8*)(VtC + fr * 136 + kb + fg * 8);
      __asm__ volatile("" ::: "memory");
      acco = __builtin_amdgcn_mfma_f32_16x16x32_bf16(pf, vf, acco, 0, 0, 0);
    }
    if (c < 7) {
      if (isK) {
        *(uint4*)(&Ks[(c + 1) & 1][kpos * 24 + sh * 8]) = nxt;
      } else {
        union { u16 u[8]; uint4 v; } pk; pk.v = nxt;
        #pragma unroll
        for (int j = 0; j < 8; ++j) Vt[(c + 1) & 1][(sh * 8 + j) * 136 + su] = pk.u[j];
      }
    }
    __syncthreads();
  }

  #pragma unroll
  for (int r = 0; r < 4; ++r) {
    float l = lsum[r];
    l += __shfl_xor(l, 1); l += __shfl_xor(l, 2);
    l += __shfl_xor(l, 4); l += __shfl_xor(l, 8);
    int row = q0 + fg * 4 + r;
    attn[((size_t)(b * 1024 + row)) * 256 + h * 16 + fr] = f2bf(acco[r] / l);
  }
}

// ---------------------------------------------------------------------------
// Final instance-norm apply -> fp32 output.
// ---------------------------------------------------------------------------
__global__ void apply_kernel(const u16* __restrict__ y, const float* __restrict__ ssum,
                             const float* __restrict__ ssq, const float* __restrict__ gamma,
                             const float* __restrict__ beta, float* __restrict__ outp)
{
  int idx = (blockIdx.x * 256 + threadIdx.x) * 4;
  int e = idx & 255;
  int b = idx >> 18;
  union { u16 u[4]; uint2 v; } in;
  in.v = *(const uint2*)(y + idx);
  float ov[4];
  const float inv = 1.f / 1024.f;
  #pragma unroll
  for (int j = 0; j < 4; ++j) {
    int ej = e + j;
    float mean = ssum[b * 256 + ej] * inv;
    float var = ssq[b * 256 + ej] * inv - mean * mean;
    float rstd = rsqrtf(var + 1e-5f);
    ov[j] = (bf2f(in.u[j]) - mean) * rstd * gamma[ej] + beta[ej];
  }
  *(float4*)(outp + idx) = make_float4(ov[0], ov[1], ov[2], ov[3]);
}

// ---------------------------------------------------------------------------
extern "C" void kernel_launch(void* const* d_in, const int* in_sizes, int n_in,
                              void* d_out, int out_size, void* d_ws, size_t ws_size,
                              hipStream_t stream)
{
  const float* x      = (const float*)d_in[0];
  const float* Wq     = (const float*)d_in[1];
  const float* Wk     = (const float*)d_in[2];
  const float* Wv     = (const float*)d_in[3];
  const float* Wo     = (const float*)d_in[4];
  const float* bo     = (const float*)d_in[5];
  const float* gamma1 = (const float*)d_in[6];
  const float* beta1  = (const float*)d_in[7];
  const float* gamma2 = (const float*)d_in[8];
  const float* beta2  = (const float*)d_in[9];
  const float* W1     = (const float*)d_in[10];
  const float* b1     = (const float*)d_in[11];
  const float* W2     = (const float*)d_in[12];
  const float* b2     = (const float*)d_in[13];

  // Workspace (49.3 MB peak, lifetime-aliased) — same layout as r7:
  char* ws = (char*)d_ws;
  u16*   WQKVT = (u16*)(ws + 0);
  u16*   WOT   = (u16*)(ws + 393216);
  u16*   W1T   = (u16*)(ws + 524288);
  u16*   W2T   = (u16*)(ws + 1048576);
  float* SS    = (float*)(ws + 1310720);
  float* SSUM1 = SS;
  float* SSQ1  = SS + 4096;
  float* SSUM2 = SS + 8192;
  float* SSQ2  = SS + 12288;
  u16*   xb    = (u16*)(ws + 1376256);
  u16*   Qb    = (u16*)(ws + 9764864);
  u16*   ATTN  = (u16*)(ws + 34930688);
  u16*   Y1    = (u16*)(ws + 9764864);
  u16*   G     = (u16*)(ws + 18153472);
  u16*   Y2    = (u16*)(ws + 34930688);

  prep_kernel<<<2688, 256, 0, stream>>>(x, xb, Wq, Wk, Wv, Wo, W1, W2,
                                        WQKVT, WOT, W1T, W2T, SS);

  gemm_kernel<MODE_QKV, 128, 0, 0, 0><<<dim3(128, 6), 256, 0, stream>>>(
      xb, WQKVT, 16384, 768, 256, nullptr, nullptr, Qb,
      nullptr, nullptr, nullptr, nullptr, nullptr, nullptr);

  attn_kernel<<<2048, 512, 0, stream>>>(Qb, Qb + 4194304, Qb + 8388608, ATTN);

  gemm_kernel<MODE_Y_RES, 64, 1, 1, 0><<<dim3(128, 4), 256, 0, stream>>>(
      ATTN, WOT, 16384, 256, 256, bo, xb, Y1,
      SSUM1, SSQ1, nullptr, nullptr, nullptr, nullptr);

  gemm_kernel<MODE_GLU, 128, 0, 0, 1><<<dim3(128, 8), 256, 0, stream>>>(
      Y1, W1T, 16384, 1024, 256, b1, nullptr, G,
      nullptr, nullptr, SSUM1, SSQ1, gamma1, beta1);

  gemm_kernel<MODE_Y_RES, 64, 2, 1, 0><<<dim3(128, 4), 256, 0, stream>>>(
      G, W2T, 16384, 256, 512, b2, Y1, Y2,
      SSUM2, SSQ2, SSUM1, SSQ1, gamma1, beta1);

  apply_kernel<<<4096, 256, 0, stream>>>(Y2, SSUM2, SSQ2, gamma2, beta2, (float*)d_out);
}

// Round 9
// 215.437 us; speedup vs baseline: 1.2899x; 1.2899x over previous
//
#include <hip/hip_runtime.h>
#include <stdint.h>

typedef unsigned short u16;
typedef __bf16 bf16x8 __attribute__((ext_vector_type(8)));
typedef float f32x4 __attribute__((ext_vector_type(4)));

__device__ __forceinline__ float bf2f(u16 v){ return __uint_as_float(((unsigned)v)<<16); }
__device__ __forceinline__ u16 f2bf(float f){
  unsigned u = __float_as_uint(f);
  unsigned r = (u + 0x7FFFu + ((u>>16)&1u)) >> 16;
  return (u16)r;
}
__device__ __forceinline__ float fexp2(float x){
#if __has_builtin(__builtin_amdgcn_exp2f)
  return __builtin_amdgcn_exp2f(x);
#else
  return exp2f(x);
#endif
}

// ---------------------------------------------------------------------------
// Prep: weight transpose fp32->bf16 [n][k] (blocks 0-639; blocks 0-63 also
// zero stats) + x fp32->bf16 (blocks 640-2687). W1 column-interleaved.
// ---------------------------------------------------------------------------
__global__ void prep_kernel(const float* __restrict__ x_, u16* __restrict__ xb,
                            const float* __restrict__ Wq, const float* __restrict__ Wk,
                            const float* __restrict__ Wv, const float* __restrict__ Wo,
                            const float* __restrict__ W1, const float* __restrict__ W2,
                            u16* __restrict__ wqkvT, u16* __restrict__ woT,
                            u16* __restrict__ w1T, u16* __restrict__ w2T,
                            float* __restrict__ SS)
{
  int bid = blockIdx.x;
  int t = threadIdx.x;
  if (bid >= 640) {
    int idx = ((bid - 640) * 256 + t) * 8;
    float4 a0 = *(const float4*)(x_ + idx);
    float4 a1 = *(const float4*)(x_ + idx + 4);
    union { u16 u[8]; uint4 v; } pk;
    pk.u[0] = f2bf(a0.x); pk.u[1] = f2bf(a0.y); pk.u[2] = f2bf(a0.z); pk.u[3] = f2bf(a0.w);
    pk.u[4] = f2bf(a1.x); pk.u[5] = f2bf(a1.y); pk.u[6] = f2bf(a1.z); pk.u[7] = f2bf(a1.w);
    *(uint4*)(xb + idx) = pk.v;
    return;
  }
  if (bid < 64) SS[bid * 256 + t] = 0.f;
  __shared__ u16 tile[32][33];
  const float* in; u16* out; int K, N, t2; bool glu = false;
  if (bid < 64)       { in = Wq; out = wqkvT;           K = 256; N = 256;  t2 = bid; }
  else if (bid < 128) { in = Wk; out = wqkvT + 65536;   K = 256; N = 256;  t2 = bid - 64; }
  else if (bid < 192) { in = Wv; out = wqkvT + 131072;  K = 256; N = 256;  t2 = bid - 128; }
  else if (bid < 256) { in = Wo; out = woT;             K = 256; N = 256;  t2 = bid - 192; }
  else if (bid < 512) { in = W1; out = w1T;             K = 256; N = 1024; t2 = bid - 256; glu = true; }
  else                { in = W2; out = w2T;             K = 512; N = 256;  t2 = bid - 512; }
  int ntn = N >> 5;
  int k0 = (t2 / ntn) * 32, n0 = (t2 % ntn) * 32;
  #pragma unroll
  for (int p = 0; p < 4; ++p) {
    int u = t + p * 256; int r = u >> 5, c = u & 31;
    tile[r][c] = f2bf(in[(size_t)(k0 + r) * N + n0 + c]);
  }
  __syncthreads();
  #pragma unroll
  for (int p = 0; p < 4; ++p) {
    int u = t + p * 256; int r = u >> 5, c = u & 31;
    int q = n0 + r;
    int row = glu ? (q < 512 ? 2 * q : 2 * (q - 512) + 1) : q;
    out[(size_t)row * K + k0 + c] = tile[c][r];
  }
}

// ---------------------------------------------------------------------------
// GEMM (r7 version, reverted): 128xTN tile, BK=32, direct staging.
// ---------------------------------------------------------------------------
enum { MODE_QKV = 0, MODE_Y_RES = 1, MODE_GLU = 2 };

template<int MODE, int TN, int RESN, int STATS, int NORMA>
__launch_bounds__(256, 3)
__global__ void gemm_kernel(const u16* __restrict__ A, const u16* __restrict__ BT,
                            int M, int N, int K,
                            const float* __restrict__ bias, const u16* __restrict__ resp,
                            u16* __restrict__ outB,
                            float* __restrict__ ssum, float* __restrict__ ssq,
                            const float* __restrict__ nsum, const float* __restrict__ nsq,
                            const float* __restrict__ ngam, const float* __restrict__ nbet)
{
  constexpr int NJ = TN / 32;          // 4 for TN=128, 2 for TN=64
  __shared__ u16 As[128 * 40];
  __shared__ u16 Bs[TN * 40];
  __shared__ float scA[256], sfA[256];
  const int t = threadIdx.x;
  const int m0 = blockIdx.x * 128;
  const int n0 = blockIdx.y * TN;
  const int lane = t & 63;
  const int w = t >> 6;
  const int wm = (w >> 1) * 64;
  const int wn = (w & 1) * (NJ * 16);
  const int fr = lane & 15;
  const int fg = lane >> 4;
  const int bIdx = m0 >> 10;
  const float inv1024 = 1.f / 1024.f;

  if (NORMA) {
    int e = t;
    float mean = nsum[bIdx * 256 + e] * inv1024;
    float var = nsq[bIdx * 256 + e] * inv1024 - mean * mean;
    float rstd = rsqrtf(var + 1e-5f);
    float sc = rstd * ngam[e];
    scA[e] = sc;
    sfA[e] = nbet[e] - mean * sc;
  }

  f32x4 acc[4][NJ];
  #pragma unroll
  for (int i = 0; i < 4; ++i)
    #pragma unroll
    for (int j = 0; j < NJ; ++j)
      acc[i][j] = (f32x4){0.f, 0.f, 0.f, 0.f};

  constexpr int TOT = (128 + TN) * 4;
  for (int k0 = 0; k0 < K; k0 += 32) {
    __syncthreads();
    #pragma unroll
    for (int u = 0; u < TOT / 256; ++u) {
      int uu = t + u * 256;
      if (uu < 512) {
        int row = uu >> 2, cb = uu & 3;
        if (NORMA) {
          union { u16 u[8]; uint4 v; } in, o;
          in.v = *(const uint4*)(A + (size_t)(m0 + row) * K + k0 + cb * 8);
          const float* scp = scA + k0 + cb * 8;
          const float* sfp = sfA + k0 + cb * 8;
          float4 s0 = *(const float4*)scp, s1 = *(const float4*)(scp + 4);
          float4 f0 = *(const float4*)sfp, f1 = *(const float4*)(sfp + 4);
          o.u[0] = f2bf(bf2f(in.u[0]) * s0.x + f0.x);
          o.u[1] = f2bf(bf2f(in.u[1]) * s0.y + f0.y);
          o.u[2] = f2bf(bf2f(in.u[2]) * s0.z + f0.z);
          o.u[3] = f2bf(bf2f(in.u[3]) * s0.w + f0.w);
          o.u[4] = f2bf(bf2f(in.u[4]) * s1.x + f1.x);
          o.u[5] = f2bf(bf2f(in.u[5]) * s1.y + f1.y);
          o.u[6] = f2bf(bf2f(in.u[6]) * s1.z + f1.z);
          o.u[7] = f2bf(bf2f(in.u[7]) * s1.w + f1.w);
          *(uint4*)(As + row * 40 + cb * 8) = o.v;
        } else {
          float4 va = *(const float4*)(A + (size_t)(m0 + row) * K + k0 + cb * 8);
          *(float4*)(As + row * 40 + cb * 8) = va;
        }
      } else {
        int v2 = uu - 512;
        int row = v2 >> 2, cb = v2 & 3;
        float4 vb = *(const float4*)(BT + (size_t)(n0 + row) * K + k0 + cb * 8);
        *(float4*)(Bs + row * 40 + cb * 8) = vb;
      }
    }
    __syncthreads();
    bf16x8 af[4], bfr[NJ];
    #pragma unroll
    for (int i = 0; i < 4; ++i) af[i]  = *(const bf16x8*)(As + (wm + i * 16 + fr) * 40 + fg * 8);
    #pragma unroll
    for (int j = 0; j < NJ; ++j) bfr[j] = *(const bf16x8*)(Bs + (wn + j * 16 + fr) * 40 + fg * 8);
    #pragma unroll
    for (int i = 0; i < 4; ++i)
      #pragma unroll
      for (int j = 0; j < NJ; ++j)
        acc[i][j] = __builtin_amdgcn_mfma_f32_16x16x32_bf16(af[i], bfr[j], acc[i][j], 0, 0, 0);
  }

  #pragma unroll
  for (int j = 0; j < NJ; ++j) {
    int col = n0 + wn + j * 16 + fr;
    float bv = 0.f;
    if (MODE == MODE_Y_RES) bv = bias[col];
    if (MODE == MODE_GLU)   bv = bias[(col >> 1) + ((col & 1) << 9)];
    float scj = 0.f, sfj = 0.f;
    if (RESN == 2) {
      float mean = nsum[bIdx * 256 + col] * inv1024;
      float var = nsq[bIdx * 256 + col] * inv1024 - mean * mean;
      float rstd = rsqrtf(var + 1e-5f);
      scj = rstd * ngam[col];
      sfj = nbet[col] - mean * scj;
    }
    float sj = 0.f, qj = 0.f;
    #pragma unroll
    for (int i = 0; i < 4; ++i) {
      #pragma unroll
      for (int r = 0; r < 4; ++r) {
        int row = m0 + wm + i * 16 + fg * 4 + r;
        float v = acc[i][j][r] + bv;
        if (MODE == MODE_QKV) {
          int which = col >> 8, h = (col >> 4) & 15, d = col & 15;
          int b = row >> 10, ns = row & 1023;
          outB[(size_t)which * 4194304 + (((size_t)(b * 16 + h) * 1024 + ns) * 16 + d)] = f2bf(v);
        } else if (MODE == MODE_Y_RES) {
          size_t idx = (size_t)row * N + col;
          float rv = bf2f(resp[idx]);
          if (RESN == 2) rv = rv * scj + sfj;
          float y = v + rv;
          outB[idx] = f2bf(y);
          if (STATS) { sj += y; qj += y * y; }
        } else { // MODE_GLU
          float partner = __shfl_xor(v, 1);
          if ((fr & 1) == 0) {
            float g = partner / (1.f + __expf(-partner));  // silu(gate)
            outB[(size_t)row * 512 + (col >> 1)] = f2bf(g * v);
          }
        }
      }
    }
    if (STATS) {
      sj += __shfl_xor(sj, 16); sj += __shfl_xor(sj, 32);
      qj += __shfl_xor(qj, 16); qj += __shfl_xor(qj, 32);
      if (fg == 0) {
        atomicAdd(&ssum[bIdx * 256 + col], sj);
        atomicAdd(&ssq[bIdx * 256 + col], qj);
      }
    }
  }
}

// ---------------------------------------------------------------------------
// Attention v4: P never leaves registers. Score MFMA computes S^T (swap
// operands: A=K, B=Q), so with K staged even/odd-split (kpos), each lane
// holds S^T for keys {8*fg+2r, 8*fg+2r+1}, q=fr — exactly the B-operand
// footprint (k=fg*8+j) of the PV 16x16x32 MFMA. V^T (natural key order) is
// the A-operand via one all-lane ds_read_b128. No P LDS buffer, no per-sub
// lgkmcnt(0) drain. O comes out transposed (d=fg*4+r, q=fr).
// ---------------------------------------------------------------------------
#define SCALE_L2 0.360673760222241f   /* (1/sqrt(16)) * log2(e) */

__launch_bounds__(512, 4)
__global__ void attn_kernel(const u16* __restrict__ Q, const u16* __restrict__ Kg,
                            const u16* __restrict__ Vg, u16* __restrict__ attn)
{
  __shared__ u16 Ks[2][128 * 24];   // [buf][slot][d] d padded 16->24; even/odd split slots
  __shared__ u16 Vt[2][16 * 136];   // [buf][d][key] natural key order, pad 128->136
  const int t = threadIdx.x;
  const int bh = blockIdx.x & 255;
  const int qg = blockIdx.x >> 8;
  const int b = bh >> 4, h = bh & 15;
  const size_t base = (size_t)bh * 16384;
  const int w = t >> 6, lane = t & 63;
  const int fr = lane & 15, fg = lane >> 4;
  const int q0 = qg * 128 + w * 16;
  const f32x4 zero4 = (f32x4){0.f, 0.f, 0.f, 0.f};

  // staging roles: threads 0-255 stage K (even/odd slot permute), 256-511 V^T
  const int su = (t & 255) >> 1;    // key-in-chunk 0..127
  const int sh = t & 1;             // which 8-d half
  const bool isK = t < 256;
  const int blk = su >> 5, ii = su & 31;
  const int kpos = blk * 32 + ((ii & 1) ? 16 + (ii >> 1) : (ii >> 1));

  // Q fragment (B-operand of score MFMA), pre-scaled by SCALE_L2
  bf16x8 qf = {};
  if (fg < 2) {
    union { u16 u[8]; uint4 v; bf16x8 f; } qt;
    qt.v = *(const uint4*)(Q + base + (size_t)(q0 + fr) * 16 + fg * 8);
    #pragma unroll
    for (int j = 0; j < 8; ++j) qt.u[j] = f2bf(bf2f(qt.u[j]) * SCALE_L2);
    qf = qt.f;
  }

  // preload chunk 0
  {
    uint4 pre = isK ? *(const uint4*)(Kg + base + (size_t)su * 16 + sh * 8)
                    : *(const uint4*)(Vg + base + (size_t)su * 16 + sh * 8);
    if (isK) {
      *(uint4*)(&Ks[0][kpos * 24 + sh * 8]) = pre;
    } else {
      union { u16 u[8]; uint4 v; } pk; pk.v = pre;
      #pragma unroll
      for (int j = 0; j < 8; ++j) Vt[0][(sh * 8 + j) * 136 + su] = pk.u[j];
    }
  }
  __syncthreads();

  f32x4 acco = zero4;
  float lsum = 0.f;

  for (int c = 0; c < 8; ++c) {
    uint4 nxt;
    if (c < 7) {
      const size_t off = base + (size_t)((c + 1) * 128 + su) * 16 + sh * 8;
      nxt = isK ? *(const uint4*)(Kg + off) : *(const uint4*)(Vg + off);
    }
    const u16* KsC = Ks[c & 1];
    const u16* VtC = Vt[c & 1];
    #pragma unroll
    for (int sub = 0; sub < 4; ++sub) {
      const int kb = sub * 32;
      bf16x8 kf0 = {}, kf1 = {};
      if (fg < 2) {
        kf0 = *(const bf16x8*)(KsC + (kb + fr) * 24 + fg * 8);        // even keys
        kf1 = *(const bf16x8*)(KsC + (kb + 16 + fr) * 24 + fg * 8);   // odd keys
      }
      // S^T: A=K, B=Q.  sT0[r] = S[q=fr][key kb+8fg+2r], sT1[r] = key kb+8fg+2r+1
      f32x4 s0 = __builtin_amdgcn_mfma_f32_16x16x32_bf16(kf0, qf, zero4, 0, 0, 0);
      f32x4 s1 = __builtin_amdgcn_mfma_f32_16x16x32_bf16(kf1, qf, zero4, 0, 0, 0);
      union { unsigned d[4]; bf16x8 f; } pf;
      #pragma unroll
      for (int r = 0; r < 4; ++r) {
        float p0 = fexp2(s0[r]);
        float p1 = fexp2(s1[r]);
        lsum += p0 + p1;
        pf.d[r] = __builtin_amdgcn_perm(__float_as_uint(p1), __float_as_uint(p0), 0x07060302u);
      }
      // PV: A = V^T[d=fr][kb+fg*8 ..+7], B = pf (in-register). D = O^T.
      bf16x8 vf = *(const bf16x8*)(VtC + fr * 136 + kb + fg * 8);
      acco = __builtin_amdgcn_mfma_f32_16x16x32_bf16(vf, pf.f, acco, 0, 0, 0);
    }
    if (c < 7) {
      if (isK) {
        *(uint4*)(&Ks[(c + 1) & 1][kpos * 24 + sh * 8]) = nxt;
      } else {
        union { u16 u[8]; uint4 v; } pk; pk.v = nxt;
        #pragma unroll
        for (int j = 0; j < 8; ++j) Vt[(c + 1) & 1][(sh * 8 + j) * 136 + su] = pk.u[j];
      }
    }
    __syncthreads();
  }

  // lsum holds keys {8fg..8fg+7} partials for q=fr: reduce over fg groups.
  lsum += __shfl_xor(lsum, 16);
  lsum += __shfl_xor(lsum, 32);
  float inv = 1.f / lsum;
  // acco[r] = O[q=fr][d=fg*4+r]
  #pragma unroll
  for (int r = 0; r < 4; ++r) {
    attn[((size_t)(b * 1024 + q0 + fr)) * 256 + h * 16 + fg * 4 + r] = f2bf(acco[r] * inv);
  }
}

// ---------------------------------------------------------------------------
// Final instance-norm apply -> fp32 output.
// ---------------------------------------------------------------------------
__global__ void apply_kernel(const u16* __restrict__ y, const float* __restrict__ ssum,
                             const float* __restrict__ ssq, const float* __restrict__ gamma,
                             const float* __restrict__ beta, float* __restrict__ outp)
{
  int idx = (blockIdx.x * 256 + threadIdx.x) * 4;
  int e = idx & 255;
  int b = idx >> 18;
  union { u16 u[4]; uint2 v; } in;
  in.v = *(const uint2*)(y + idx);
  float ov[4];
  const float inv = 1.f / 1024.f;
  #pragma unroll
  for (int j = 0; j < 4; ++j) {
    int ej = e + j;
    float mean = ssum[b * 256 + ej] * inv;
    float var = ssq[b * 256 + ej] * inv - mean * mean;
    float rstd = rsqrtf(var + 1e-5f);
    ov[j] = (bf2f(in.u[j]) - mean) * rstd * gamma[ej] + beta[ej];
  }
  *(float4*)(outp + idx) = make_float4(ov[0], ov[1], ov[2], ov[3]);
}

// ---------------------------------------------------------------------------
extern "C" void kernel_launch(void* const* d_in, const int* in_sizes, int n_in,
                              void* d_out, int out_size, void* d_ws, size_t ws_size,
                              hipStream_t stream)
{
  const float* x      = (const float*)d_in[0];
  const float* Wq     = (const float*)d_in[1];
  const float* Wk     = (const float*)d_in[2];
  const float* Wv     = (const float*)d_in[3];
  const float* Wo     = (const float*)d_in[4];
  const float* bo     = (const float*)d_in[5];
  const float* gamma1 = (const float*)d_in[6];
  const float* beta1  = (const float*)d_in[7];
  const float* gamma2 = (const float*)d_in[8];
  const float* beta2  = (const float*)d_in[9];
  const float* W1     = (const float*)d_in[10];
  const float* b1     = (const float*)d_in[11];
  const float* W2     = (const float*)d_in[12];
  const float* b2     = (const float*)d_in[13];

  // Workspace (49.3 MB peak, lifetime-aliased) — same layout as r7:
  char* ws = (char*)d_ws;
  u16*   WQKVT = (u16*)(ws + 0);
  u16*   WOT   = (u16*)(ws + 393216);
  u16*   W1T   = (u16*)(ws + 524288);
  u16*   W2T   = (u16*)(ws + 1048576);
  float* SS    = (float*)(ws + 1310720);
  float* SSUM1 = SS;
  float* SSQ1  = SS + 4096;
  float* SSUM2 = SS + 8192;
  float* SSQ2  = SS + 12288;
  u16*   xb    = (u16*)(ws + 1376256);
  u16*   Qb    = (u16*)(ws + 9764864);
  u16*   ATTN  = (u16*)(ws + 34930688);
  u16*   Y1    = (u16*)(ws + 9764864);
  u16*   G     = (u16*)(ws + 18153472);
  u16*   Y2    = (u16*)(ws + 34930688);

  prep_kernel<<<2688, 256, 0, stream>>>(x, xb, Wq, Wk, Wv, Wo, W1, W2,
                                        WQKVT, WOT, W1T, W2T, SS);

  gemm_kernel<MODE_QKV, 128, 0, 0, 0><<<dim3(128, 6), 256, 0, stream>>>(
      xb, WQKVT, 16384, 768, 256, nullptr, nullptr, Qb,
      nullptr, nullptr, nullptr, nullptr, nullptr, nullptr);

  attn_kernel<<<2048, 512, 0, stream>>>(Qb, Qb + 4194304, Qb + 8388608, ATTN);

  gemm_kernel<MODE_Y_RES, 64, 1, 1, 0><<<dim3(128, 4), 256, 0, stream>>>(
      ATTN, WOT, 16384, 256, 256, bo, xb, Y1,
      SSUM1, SSQ1, nullptr, nullptr, nullptr, nullptr);

  gemm_kernel<MODE_GLU, 128, 0, 0, 1><<<dim3(128, 8), 256, 0, stream>>>(
      Y1, W1T, 16384, 1024, 256, b1, nullptr, G,
      nullptr, nullptr, SSUM1, SSQ1, gamma1, beta1);

  gemm_kernel<MODE_Y_RES, 64, 2, 1, 0><<<dim3(128, 4), 256, 0, stream>>>(
      G, W2T, 16384, 256, 512, b2, Y1, Y2,
      SSUM2, SSQ2, SSUM1, SSQ1, gamma1, beta1);

  apply_kernel<<<4096, 256, 0, stream>>>(Y2, SSUM2, SSQ2, gamma2, beta2, (float*)d_out);
}

// Round 10
// 212.309 us; speedup vs baseline: 1.3089x; 1.0147x over previous
//
#include <hip/hip_runtime.h>
#include <stdint.h>

typedef unsigned short u16;
typedef __bf16 bf16x8 __attribute__((ext_vector_type(8)));
typedef float f32x4 __attribute__((ext_vector_type(4)));

__device__ __forceinline__ float bf2f(u16 v){ return __uint_as_float(((unsigned)v)<<16); }
__device__ __forceinline__ u16 f2bf(float f){
  unsigned u = __float_as_uint(f);
  unsigned r = (u + 0x7FFFu + ((u>>16)&1u)) >> 16;
  return (u16)r;
}
__device__ __forceinline__ float fexp2(float x){
#if __has_builtin(__builtin_amdgcn_exp2f)
  return __builtin_amdgcn_exp2f(x);
#else
  return exp2f(x);
#endif
}
// async global->LDS, 16B/lane; LDS dest = wave-uniform base + lane*16
__device__ __forceinline__ void gll16(const u16* g, u16* l){
  __builtin_amdgcn_global_load_lds(
      (const __attribute__((address_space(1))) void*)g,
      (__attribute__((address_space(3))) void*)l, 16, 0, 0);
}

// ---------------------------------------------------------------------------
// Prep: weight transpose fp32->bf16 [n][k] (blocks 0-639; blocks 0-63 also
// zero stats) + x fp32->bf16 (blocks 640-2687). W1 column-interleaved.
// ---------------------------------------------------------------------------
__global__ void prep_kernel(const float* __restrict__ x_, u16* __restrict__ xb,
                            const float* __restrict__ Wq, const float* __restrict__ Wk,
                            const float* __restrict__ Wv, const float* __restrict__ Wo,
                            const float* __restrict__ W1, const float* __restrict__ W2,
                            u16* __restrict__ wqkvT, u16* __restrict__ woT,
                            u16* __restrict__ w1T, u16* __restrict__ w2T,
                            float* __restrict__ SS)
{
  int bid = blockIdx.x;
  int t = threadIdx.x;
  if (bid >= 640) {
    int idx = ((bid - 640) * 256 + t) * 8;
    float4 a0 = *(const float4*)(x_ + idx);
    float4 a1 = *(const float4*)(x_ + idx + 4);
    union { u16 u[8]; uint4 v; } pk;
    pk.u[0] = f2bf(a0.x); pk.u[1] = f2bf(a0.y); pk.u[2] = f2bf(a0.z); pk.u[3] = f2bf(a0.w);
    pk.u[4] = f2bf(a1.x); pk.u[5] = f2bf(a1.y); pk.u[6] = f2bf(a1.z); pk.u[7] = f2bf(a1.w);
    *(uint4*)(xb + idx) = pk.v;
    return;
  }
  if (bid < 64) SS[bid * 256 + t] = 0.f;
  __shared__ u16 tile[32][33];
  const float* in; u16* out; int K, N, t2; bool glu = false;
  if (bid < 64)       { in = Wq; out = wqkvT;           K = 256; N = 256;  t2 = bid; }
  else if (bid < 128) { in = Wk; out = wqkvT + 65536;   K = 256; N = 256;  t2 = bid - 64; }
  else if (bid < 192) { in = Wv; out = wqkvT + 131072;  K = 256; N = 256;  t2 = bid - 128; }
  else if (bid < 256) { in = Wo; out = woT;             K = 256; N = 256;  t2 = bid - 192; }
  else if (bid < 512) { in = W1; out = w1T;             K = 256; N = 1024; t2 = bid - 256; glu = true; }
  else                { in = W2; out = w2T;             K = 512; N = 256;  t2 = bid - 512; }
  int ntn = N >> 5;
  int k0 = (t2 / ntn) * 32, n0 = (t2 % ntn) * 32;
  #pragma unroll
  for (int p = 0; p < 4; ++p) {
    int u = t + p * 256; int r = u >> 5, c = u & 31;
    tile[r][c] = f2bf(in[(size_t)(k0 + r) * N + n0 + c]);
  }
  __syncthreads();
  #pragma unroll
  for (int p = 0; p < 4; ++p) {
    int u = t + p * 256; int r = u >> 5, c = u & 31;
    int q = n0 + r;
    int row = glu ? (q < 512 ? 2 * q : 2 * (q - 512) + 1) : q;
    out[(size_t)row * K + k0 + c] = tile[c][r];
  }
}

// ---------------------------------------------------------------------------
// GEMM v3 (m97 shape): 128xTN tile, BK=32, unpadded stride-32 LDS tiles,
// global_load_lds width-16 staging (A when !NORMA, B always).
// ---------------------------------------------------------------------------
enum { MODE_QKV = 0, MODE_Y_RES = 1, MODE_GLU = 2 };

template<int MODE, int TN, int RESN, int STATS, int NORMA>
__launch_bounds__(256, 3)
__global__ void gemm_kernel(const u16* __restrict__ A, const u16* __restrict__ BT,
                            int M, int N, int K,
                            const float* __restrict__ bias, const u16* __restrict__ resp,
                            u16* __restrict__ outB,
                            float* __restrict__ ssum, float* __restrict__ ssq,
                            const float* __restrict__ nsum, const float* __restrict__ nsq,
                            const float* __restrict__ ngam, const float* __restrict__ nbet)
{
  constexpr int NJ = TN / 32;          // 4 for TN=128, 2 for TN=64
  __shared__ u16 As[128 * 32];
  __shared__ u16 Bs[TN * 32];
  __shared__ float scA[256], sfA[256];
  const int t = threadIdx.x;
  const int m0 = blockIdx.x * 128;
  const int n0 = blockIdx.y * TN;
  const int lane = t & 63;
  const int w = t >> 6;
  const int wm = (w >> 1) * 64;
  const int wn = (w & 1) * (NJ * 16);
  const int fr = lane & 15;
  const int fg = lane >> 4;
  const int bIdx = m0 >> 10;
  const float inv1024 = 1.f / 1024.f;
  const int glr = lane >> 2;           // gll row-in-group 0..15
  const int gcb = (lane & 3) * 8;      // gll 16B col block

  if (NORMA) {
    int e = t;
    float mean = nsum[bIdx * 256 + e] * inv1024;
    float var = nsq[bIdx * 256 + e] * inv1024 - mean * mean;
    float rstd = rsqrtf(var + 1e-5f);
    float sc = rstd * ngam[e];
    scA[e] = sc;
    sfA[e] = nbet[e] - mean * sc;
  }

  f32x4 acc[4][NJ];
  #pragma unroll
  for (int i = 0; i < 4; ++i)
    #pragma unroll
    for (int j = 0; j < NJ; ++j)
      acc[i][j] = (f32x4){0.f, 0.f, 0.f, 0.f};

  for (int k0 = 0; k0 < K; k0 += 32) {
    __syncthreads();                       // prev tiles fully read
    if (!NORMA) {
      size_t arow = (size_t)(m0 + w * 32 + glr);
      gll16(A + arow * K + k0 + gcb,        As + w * 1024);
      gll16(A + (arow + 16) * K + k0 + gcb, As + w * 1024 + 512);
    } else {
      #pragma unroll
      for (int u = 0; u < 2; ++u) {
        int uu = t + u * 256;
        int row = uu >> 2, cb = uu & 3;
        union { u16 u[8]; uint4 v; } in, o;
        in.v = *(const uint4*)(A + (size_t)(m0 + row) * K + k0 + cb * 8);
        const float* scp = scA + k0 + cb * 8;
        const float* sfp = sfA + k0 + cb * 8;
        #pragma unroll
        for (int q = 0; q < 8; ++q) o.u[q] = f2bf(bf2f(in.u[q]) * scp[q] + sfp[q]);
        *(uint4*)(As + row * 32 + cb * 8) = o.v;
      }
    }
    if (TN == 128) {
      size_t brow = (size_t)(n0 + w * 32 + glr);
      gll16(BT + brow * K + k0 + gcb,        Bs + w * 1024);
      gll16(BT + (brow + 16) * K + k0 + gcb, Bs + w * 1024 + 512);
    } else {
      size_t brow = (size_t)(n0 + w * 16 + glr);
      gll16(BT + brow * K + k0 + gcb, Bs + w * 512);
    }
    __syncthreads();                       // drains vmcnt+lgkm: tiles ready
    bf16x8 af[4], bfr[NJ];
    #pragma unroll
    for (int i = 0; i < 4; ++i) af[i]  = *(const bf16x8*)(As + (wm + i * 16 + fr) * 32 + fg * 8);
    #pragma unroll
    for (int j = 0; j < NJ; ++j) bfr[j] = *(const bf16x8*)(Bs + (wn + j * 16 + fr) * 32 + fg * 8);
    #pragma unroll
    for (int i = 0; i < 4; ++i)
      #pragma unroll
      for (int j = 0; j < NJ; ++j)
        acc[i][j] = __builtin_amdgcn_mfma_f32_16x16x32_bf16(af[i], bfr[j], acc[i][j], 0, 0, 0);
  }

  #pragma unroll
  for (int j = 0; j < NJ; ++j) {
    int col = n0 + wn + j * 16 + fr;
    float bv = 0.f;
    if (MODE == MODE_Y_RES) bv = bias[col];
    if (MODE == MODE_GLU)   bv = bias[(col >> 1) + ((col & 1) << 9)];
    float scj = 0.f, sfj = 0.f;
    if (RESN == 2) {
      float mean = nsum[bIdx * 256 + col] * inv1024;
      float var = nsq[bIdx * 256 + col] * inv1024 - mean * mean;
      float rstd = rsqrtf(var + 1e-5f);
      scj = rstd * ngam[col];
      sfj = nbet[col] - mean * scj;
    }
    float sj = 0.f, qj = 0.f;
    #pragma unroll
    for (int i = 0; i < 4; ++i) {
      #pragma unroll
      for (int r = 0; r < 4; ++r) {
        int row = m0 + wm + i * 16 + fg * 4 + r;
        float v = acc[i][j][r] + bv;
        if (MODE == MODE_QKV) {
          int which = col >> 8, h = (col >> 4) & 15, d = col & 15;
          int b = row >> 10, ns = row & 1023;
          size_t idx;
          if (which == 2)   // V stored d-major: [b][h][d][n]
            idx = (size_t)2 * 4194304 + ((size_t)(b * 16 + h)) * 16384 + d * 1024 + ns;
          else
            idx = (size_t)which * 4194304 + (((size_t)(b * 16 + h) * 1024 + ns) * 16 + d);
          outB[idx] = f2bf(v);
        } else if (MODE == MODE_Y_RES) {
          size_t idx = (size_t)row * N + col;
          float rv = bf2f(resp[idx]);
          if (RESN == 2) rv = rv * scj + sfj;
          float y = v + rv;
          outB[idx] = f2bf(y);
          if (STATS) { sj += y; qj += y * y; }
        } else { // MODE_GLU
          float partner = __shfl_xor(v, 1);
          if ((fr & 1) == 0) {
            float g = partner / (1.f + __expf(-partner));  // silu(gate)
            outB[(size_t)row * 512 + (col >> 1)] = f2bf(g * v);
          }
        }
      }
    }
    if (STATS) {
      sj += __shfl_xor(sj, 16); sj += __shfl_xor(sj, 32);
      qj += __shfl_xor(qj, 16); qj += __shfl_xor(qj, 32);
      if (fg == 0) {
        atomicAdd(&ssum[bIdx * 256 + col], sj);
        atomicAdd(&ssq[bIdx * 256 + col], qj);
      }
    }
  }
}

// ---------------------------------------------------------------------------
// Attention v5: in-register P (v4 math) + async staging.
// K staged via global_load_lds with even/odd permute folded into the global
// source address (unpadded Ks stride 16). V arrives d-major [b][h][d][n] so
// V^T staging is one uint4 load + one ds_write_b128 per thread per chunk.
// ---------------------------------------------------------------------------
#define SCALE_L2 0.360673760222241f   /* (1/sqrt(16)) * log2(e) */

__launch_bounds__(512, 4)
__global__ void attn_kernel(const u16* __restrict__ Q, const u16* __restrict__ Kg,
                            const u16* __restrict__ Vg, u16* __restrict__ attn)
{
  __shared__ u16 Ks[2][128 * 16];   // [buf][slot][d] even/odd-split slots, unpadded
  __shared__ u16 Vt[2][16 * 136];   // [buf][d][key] natural keys, pad 128->136
  const int t = threadIdx.x;
  const int bh = blockIdx.x & 255;
  const int qg = blockIdx.x >> 8;
  const int b = bh >> 4, h = bh & 15;
  const size_t base = (size_t)bh * 16384;
  const int w = t >> 6, lane = t & 63;
  const int fr = lane & 15, fg = lane >> 4;
  const int q0 = qg * 128 + w * 16;
  const f32x4 zero4 = (f32x4){0.f, 0.f, 0.f, 0.f};
  const bool isK = t < 256;

  // K gll mapping (waves 0-3): slot = 32w + lane/2 -> global key inverse-permuted
  const int si = lane >> 1;
  const int halfo = (lane & 1) * 8;
  const int keyloc = (si < 16) ? (2 * si) : (2 * (si - 16) + 1);
  // V mapping (waves 4-7)
  const int unit = t - 256;
  const int vd = unit >> 4, voct = unit & 15;

  // Q fragment (B-operand of S^T MFMA), pre-scaled by SCALE_L2
  bf16x8 qf = {};
  if (fg < 2) {
    union { u16 u[8]; uint4 v; bf16x8 f; } qt;
    qt.v = *(const uint4*)(Q + base + (size_t)(q0 + fr) * 16 + fg * 8);
    #pragma unroll
    for (int j = 0; j < 8; ++j) qt.u[j] = f2bf(bf2f(qt.u[j]) * SCALE_L2);
    qf = qt.f;
  }

  // preload chunk 0
  if (isK) {
    gll16(Kg + base + (size_t)(32 * w + keyloc) * 16 + halfo, &Ks[0][0] + w * 512);
  } else {
    uint4 v = *(const uint4*)(Vg + base + vd * 1024 + voct * 8);
    *(uint4*)(&Vt[0][vd * 136 + voct * 8]) = v;
  }
  __syncthreads();

  f32x4 acco = zero4;
  float lsum = 0.f;

  for (int c = 0; c < 8; ++c) {
    uint4 nxt;
    if (c < 7) {
      if (isK)
        gll16(Kg + base + (size_t)((c + 1) * 128 + 32 * w + keyloc) * 16 + halfo,
              &Ks[(c + 1) & 1][0] + w * 512);
      else
        nxt = *(const uint4*)(Vg + base + vd * 1024 + (c + 1) * 128 + voct * 8);
    }
    const u16* KsC = Ks[c & 1];
    const u16* VtC = Vt[c & 1];
    #pragma unroll
    for (int sub = 0; sub < 4; ++sub) {
      const int kb = sub * 32;
      bf16x8 kf0 = {}, kf1 = {};
      if (fg < 2) {
        kf0 = *(const bf16x8*)(KsC + (kb + fr) * 16 + fg * 8);        // even keys
        kf1 = *(const bf16x8*)(KsC + (kb + 16 + fr) * 16 + fg * 8);   // odd keys
      }
      f32x4 s0 = __builtin_amdgcn_mfma_f32_16x16x32_bf16(kf0, qf, zero4, 0, 0, 0);
      f32x4 s1 = __builtin_amdgcn_mfma_f32_16x16x32_bf16(kf1, qf, zero4, 0, 0, 0);
      union { unsigned d[4]; bf16x8 f; } pf;
      #pragma unroll
      for (int r = 0; r < 4; ++r) {
        float p0 = fexp2(s0[r]);
        float p1 = fexp2(s1[r]);
        lsum += p0 + p1;
        pf.d[r] = __builtin_amdgcn_perm(__float_as_uint(p1), __float_as_uint(p0), 0x07060302u);
      }
      bf16x8 vf = *(const bf16x8*)(VtC + fr * 136 + kb + fg * 8);
      acco = __builtin_amdgcn_mfma_f32_16x16x32_bf16(vf, pf.f, acco, 0, 0, 0);
    }
    if (c < 7 && !isK)
      *(uint4*)(&Vt[(c + 1) & 1][vd * 136 + voct * 8]) = nxt;
    __syncthreads();
  }

  lsum += __shfl_xor(lsum, 16);
  lsum += __shfl_xor(lsum, 32);
  float inv = 1.f / lsum;
  union { u16 u[4]; uint2 v; } ov;
  #pragma unroll
  for (int r = 0; r < 4; ++r) ov.u[r] = f2bf(acco[r] * inv);
  *(uint2*)(attn + ((size_t)(b * 1024 + q0 + fr)) * 256 + h * 16 + fg * 4) = ov.v;
}

// ---------------------------------------------------------------------------
// Final instance-norm apply -> fp32 output.
// ---------------------------------------------------------------------------
__global__ void apply_kernel(const u16* __restrict__ y, const float* __restrict__ ssum,
                             const float* __restrict__ ssq, const float* __restrict__ gamma,
                             const float* __restrict__ beta, float* __restrict__ outp)
{
  int idx = (blockIdx.x * 256 + threadIdx.x) * 4;
  int e = idx & 255;
  int b = idx >> 18;
  union { u16 u[4]; uint2 v; } in;
  in.v = *(const uint2*)(y + idx);
  float ov[4];
  const float inv = 1.f / 1024.f;
  #pragma unroll
  for (int j = 0; j < 4; ++j) {
    int ej = e + j;
    float mean = ssum[b * 256 + ej] * inv;
    float var = ssq[b * 256 + ej] * inv - mean * mean;
    float rstd = rsqrtf(var + 1e-5f);
    ov[j] = (bf2f(in.u[j]) - mean) * rstd * gamma[ej] + beta[ej];
  }
  *(float4*)(outp + idx) = make_float4(ov[0], ov[1], ov[2], ov[3]);
}

// ---------------------------------------------------------------------------
extern "C" void kernel_launch(void* const* d_in, const int* in_sizes, int n_in,
                              void* d_out, int out_size, void* d_ws, size_t ws_size,
                              hipStream_t stream)
{
  const float* x      = (const float*)d_in[0];
  const float* Wq     = (const float*)d_in[1];
  const float* Wk     = (const float*)d_in[2];
  const float* Wv     = (const float*)d_in[3];
  const float* Wo     = (const float*)d_in[4];
  const float* bo     = (const float*)d_in[5];
  const float* gamma1 = (const float*)d_in[6];
  const float* beta1  = (const float*)d_in[7];
  const float* gamma2 = (const float*)d_in[8];
  const float* beta2  = (const float*)d_in[9];
  const float* W1     = (const float*)d_in[10];
  const float* b1     = (const float*)d_in[11];
  const float* W2     = (const float*)d_in[12];
  const float* b2     = (const float*)d_in[13];

  // Workspace (49.3 MB peak, lifetime-aliased) — same layout as r7/r9:
  char* ws = (char*)d_ws;
  u16*   WQKVT = (u16*)(ws + 0);
  u16*   WOT   = (u16*)(ws + 393216);
  u16*   W1T   = (u16*)(ws + 524288);
  u16*   W2T   = (u16*)(ws + 1048576);
  float* SS    = (float*)(ws + 1310720);
  float* SSUM1 = SS;
  float* SSQ1  = SS + 4096;
  float* SSUM2 = SS + 8192;
  float* SSQ2  = SS + 12288;
  u16*   xb    = (u16*)(ws + 1376256);
  u16*   Qb    = (u16*)(ws + 9764864);
  u16*   ATTN  = (u16*)(ws + 34930688);
  u16*   Y1    = (u16*)(ws + 9764864);
  u16*   G     = (u16*)(ws + 18153472);
  u16*   Y2    = (u16*)(ws + 34930688);

  prep_kernel<<<2688, 256, 0, stream>>>(x, xb, Wq, Wk, Wv, Wo, W1, W2,
                                        WQKVT, WOT, W1T, W2T, SS);

  gemm_kernel<MODE_QKV, 128, 0, 0, 0><<<dim3(128, 6), 256, 0, stream>>>(
      xb, WQKVT, 16384, 768, 256, nullptr, nullptr, Qb,
      nullptr, nullptr, nullptr, nullptr, nullptr, nullptr);

  attn_kernel<<<2048, 512, 0, stream>>>(Qb, Qb + 4194304, Qb + 8388608, ATTN);

  gemm_kernel<MODE_Y_RES, 64, 1, 1, 0><<<dim3(128, 4), 256, 0, stream>>>(
      ATTN, WOT, 16384, 256, 256, bo, xb, Y1,
      SSUM1, SSQ1, nullptr, nullptr, nullptr, nullptr);

  gemm_kernel<MODE_GLU, 128, 0, 0, 1><<<dim3(128, 8), 256, 0, stream>>>(
      Y1, W1T, 16384, 1024, 256, b1, nullptr, G,
      nullptr, nullptr, SSUM1, SSQ1, gamma1, beta1);

  gemm_kernel<MODE_Y_RES, 64, 2, 1, 0><<<dim3(128, 4), 256, 0, stream>>>(
      G, W2T, 16384, 256, 512, b2, Y1, Y2,
      SSUM2, SSQ2, SSUM1, SSQ1, gamma1, beta1);

  apply_kernel<<<4096, 256, 0, stream>>>(Y2, SSUM2, SSQ2, gamma2, beta2, (float*)d_out);
}

// Round 11
// 204.229 us; speedup vs baseline: 1.3607x; 1.0396x over previous
//
#include <hip/hip_runtime.h>
#include <stdint.h>

typedef unsigned short u16;
typedef __bf16 bf16x8 __attribute__((ext_vector_type(8)));
typedef float f32x4 __attribute__((ext_vector_type(4)));

__device__ __forceinline__ float bf2f(u16 v){ return __uint_as_float(((unsigned)v)<<16); }
__device__ __forceinline__ u16 f2bf(float f){
  unsigned u = __float_as_uint(f);
  unsigned r = (u + 0x7FFFu + ((u>>16)&1u)) >> 16;
  return (u16)r;
}
__device__ __forceinline__ float fexp2(float x){
#if __has_builtin(__builtin_amdgcn_exp2f)
  return __builtin_amdgcn_exp2f(x);
#else
  return exp2f(x);
#endif
}
// async global->LDS, 16B/lane; LDS dest = wave-uniform base + lane*16
__device__ __forceinline__ void gll16(const u16* g, u16* l){
  __builtin_amdgcn_global_load_lds(
      (const __attribute__((address_space(1))) void*)g,
      (__attribute__((address_space(3))) void*)l, 16, 0, 0);
}

// ---------------------------------------------------------------------------
// Prep: weight transpose fp32->bf16 [n][k] (blocks 0-639; blocks 0-63 also
// zero stats) + x fp32->bf16 (blocks 640-2687). W1 column-interleaved.
// ---------------------------------------------------------------------------
__global__ void prep_kernel(const float* __restrict__ x_, u16* __restrict__ xb,
                            const float* __restrict__ Wq, const float* __restrict__ Wk,
                            const float* __restrict__ Wv, const float* __restrict__ Wo,
                            const float* __restrict__ W1, const float* __restrict__ W2,
                            u16* __restrict__ wqkvT, u16* __restrict__ woT,
                            u16* __restrict__ w1T, u16* __restrict__ w2T,
                            float* __restrict__ SS)
{
  int bid = blockIdx.x;
  int t = threadIdx.x;
  if (bid >= 640) {
    int idx = ((bid - 640) * 256 + t) * 8;
    float4 a0 = *(const float4*)(x_ + idx);
    float4 a1 = *(const float4*)(x_ + idx + 4);
    union { u16 u[8]; uint4 v; } pk;
    pk.u[0] = f2bf(a0.x); pk.u[1] = f2bf(a0.y); pk.u[2] = f2bf(a0.z); pk.u[3] = f2bf(a0.w);
    pk.u[4] = f2bf(a1.x); pk.u[5] = f2bf(a1.y); pk.u[6] = f2bf(a1.z); pk.u[7] = f2bf(a1.w);
    *(uint4*)(xb + idx) = pk.v;
    return;
  }
  if (bid < 64) SS[bid * 256 + t] = 0.f;
  __shared__ u16 tile[32][33];
  const float* in; u16* out; int K, N, t2; bool glu = false;
  if (bid < 64)       { in = Wq; out = wqkvT;           K = 256; N = 256;  t2 = bid; }
  else if (bid < 128) { in = Wk; out = wqkvT + 65536;   K = 256; N = 256;  t2 = bid - 64; }
  else if (bid < 192) { in = Wv; out = wqkvT + 131072;  K = 256; N = 256;  t2 = bid - 128; }
  else if (bid < 256) { in = Wo; out = woT;             K = 256; N = 256;  t2 = bid - 192; }
  else if (bid < 512) { in = W1; out = w1T;             K = 256; N = 1024; t2 = bid - 256; glu = true; }
  else                { in = W2; out = w2T;             K = 512; N = 256;  t2 = bid - 512; }
  int ntn = N >> 5;
  int k0 = (t2 / ntn) * 32, n0 = (t2 % ntn) * 32;
  #pragma unroll
  for (int p = 0; p < 4; ++p) {
    int u = t + p * 256; int r = u >> 5, c = u & 31;
    tile[r][c] = f2bf(in[(size_t)(k0 + r) * N + n0 + c]);
  }
  __syncthreads();
  #pragma unroll
  for (int p = 0; p < 4; ++p) {
    int u = t + p * 256; int r = u >> 5, c = u & 31;
    int q = n0 + r;
    int row = glu ? (q < 512 ? 2 * q : 2 * (q - 512) + 1) : q;
    out[(size_t)row * K + k0 + c] = tile[c][r];
  }
}

// ---------------------------------------------------------------------------
// GEMM v4: m97-style staging + SWAPPED MFMA operands (C^T fragment: lane
// fr = m-row, regs = 4 consecutive n-cols) -> fully vectorized epilogues.
// ---------------------------------------------------------------------------
enum { MODE_QKV = 0, MODE_Y_RES = 1, MODE_GLU = 2 };

template<int MODE, int TN, int RESN, int STATS, int NORMA>
__launch_bounds__(256, 3)
__global__ void gemm_kernel(const u16* __restrict__ A, const u16* __restrict__ BT,
                            int M, int N, int K,
                            const float* __restrict__ bias, const u16* __restrict__ resp,
                            u16* __restrict__ outB,
                            float* __restrict__ ssum, float* __restrict__ ssq,
                            const float* __restrict__ nsum, const float* __restrict__ nsq,
                            const float* __restrict__ ngam, const float* __restrict__ nbet)
{
  constexpr int NJ = TN / 32;          // 4 for TN=128, 2 for TN=64
  __shared__ u16 As[128 * 32];
  __shared__ u16 Bs[TN * 32];
  __shared__ float scA[256], sfA[256];
  const int t = threadIdx.x;
  const int m0 = blockIdx.x * 128;
  const int n0 = blockIdx.y * TN;
  const int lane = t & 63;
  const int w = t >> 6;
  const int wm = (w >> 1) * 64;
  const int wn = (w & 1) * (NJ * 16);
  const int fr = lane & 15;
  const int fg = lane >> 4;
  const int bIdx = m0 >> 10;
  const float inv1024 = 1.f / 1024.f;
  const int glr = lane >> 2;           // gll row-in-group 0..15
  const int gcb = (lane & 3) * 8;      // gll 16B col block

  if (NORMA) {
    int e = t;
    float mean = nsum[bIdx * 256 + e] * inv1024;
    float var = nsq[bIdx * 256 + e] * inv1024 - mean * mean;
    float rstd = rsqrtf(var + 1e-5f);
    float sc = rstd * ngam[e];
    scA[e] = sc;
    sfA[e] = nbet[e] - mean * sc;
  }

  f32x4 acc[4][NJ];
  #pragma unroll
  for (int i = 0; i < 4; ++i)
    #pragma unroll
    for (int j = 0; j < NJ; ++j)
      acc[i][j] = (f32x4){0.f, 0.f, 0.f, 0.f};

  for (int k0 = 0; k0 < K; k0 += 32) {
    __syncthreads();
    if (!NORMA) {
      size_t arow = (size_t)(m0 + w * 32 + glr);
      gll16(A + arow * K + k0 + gcb,        As + w * 1024);
      gll16(A + (arow + 16) * K + k0 + gcb, As + w * 1024 + 512);
    } else {
      #pragma unroll
      for (int u = 0; u < 2; ++u) {
        int uu = t + u * 256;
        int row = uu >> 2, cb = uu & 3;
        union { u16 u[8]; uint4 v; } in, o;
        in.v = *(const uint4*)(A + (size_t)(m0 + row) * K + k0 + cb * 8);
        const float* scp = scA + k0 + cb * 8;
        const float* sfp = sfA + k0 + cb * 8;
        #pragma unroll
        for (int q = 0; q < 8; ++q) o.u[q] = f2bf(bf2f(in.u[q]) * scp[q] + sfp[q]);
        *(uint4*)(As + row * 32 + cb * 8) = o.v;
      }
    }
    if (TN == 128) {
      size_t brow = (size_t)(n0 + w * 32 + glr);
      gll16(BT + brow * K + k0 + gcb,        Bs + w * 1024);
      gll16(BT + (brow + 16) * K + k0 + gcb, Bs + w * 1024 + 512);
    } else {
      size_t brow = (size_t)(n0 + w * 16 + glr);
      gll16(BT + brow * K + k0 + gcb, Bs + w * 512);
    }
    __syncthreads();
    bf16x8 af[4], bfr[NJ];
    #pragma unroll
    for (int i = 0; i < 4; ++i) af[i]  = *(const bf16x8*)(As + (wm + i * 16 + fr) * 32 + fg * 8);
    #pragma unroll
    for (int j = 0; j < NJ; ++j) bfr[j] = *(const bf16x8*)(Bs + (wn + j * 16 + fr) * 32 + fg * 8);
    // SWAPPED operands: D^T fragment, fr = m-row, fg*4+r = n-col
    #pragma unroll
    for (int i = 0; i < 4; ++i)
      #pragma unroll
      for (int j = 0; j < NJ; ++j)
        acc[i][j] = __builtin_amdgcn_mfma_f32_16x16x32_bf16(bfr[j], af[i], acc[i][j], 0, 0, 0);
  }

  // ---- epilogue: lane holds 4 consecutive n-cols for m-row (wm+i*16+fr) ----
  #pragma unroll
  for (int j = 0; j < NJ; ++j) {
    const int ncb = n0 + wn + j * 16 + fg * 4;   // base col (+r, r=0..3)
    float bv[4] = {0.f, 0.f, 0.f, 0.f};
    if (MODE == MODE_Y_RES) {
      float4 bl = *(const float4*)(bias + ncb);
      bv[0] = bl.x; bv[1] = bl.y; bv[2] = bl.z; bv[3] = bl.w;
    }
    if (MODE == MODE_GLU) {
      #pragma unroll
      for (int r = 0; r < 4; ++r) {
        int col = ncb + r;
        bv[r] = bias[(col >> 1) + ((col & 1) << 9)];
      }
    }
    float scj[4], sfj[4];
    if (RESN == 2) {
      float4 ns_ = *(const float4*)(nsum + bIdx * 256 + ncb);
      float4 nq_ = *(const float4*)(nsq  + bIdx * 256 + ncb);
      float4 ng_ = *(const float4*)(ngam + ncb);
      float4 nb_ = *(const float4*)(nbet + ncb);
      #pragma unroll
      for (int r = 0; r < 4; ++r) {
        float mean = (&ns_.x)[r] * inv1024;
        float var = (&nq_.x)[r] * inv1024 - mean * mean;
        float rstd = rsqrtf(var + 1e-5f);
        scj[r] = rstd * (&ng_.x)[r];
        sfj[r] = (&nb_.x)[r] - mean * scj[r];
      }
    }
    float sjr[4] = {0,0,0,0}, qjr[4] = {0,0,0,0};
    #pragma unroll
    for (int i = 0; i < 4; ++i) {
      const int mrow = m0 + wm + i * 16 + fr;
      float v[4];
      #pragma unroll
      for (int r = 0; r < 4; ++r) v[r] = acc[i][j][r] + bv[r];
      if (MODE == MODE_QKV) {
        int which = ncb >> 8, h = (ncb >> 4) & 15, d0 = ncb & 15;
        int b = mrow >> 10, ns = mrow & 1023;
        if (which < 2) {
          union { u16 u[4]; uint2 x; } pk;
          #pragma unroll
          for (int r = 0; r < 4; ++r) pk.u[r] = f2bf(v[r]);
          *(uint2*)(outB + (size_t)which * 4194304 +
                    (((size_t)(b * 16 + h) * 1024 + ns) * 16 + d0)) = pk.x;
        } else {   // V d-major [b][h][d][n]
          #pragma unroll
          for (int r = 0; r < 4; ++r)
            outB[(size_t)2 * 4194304 + ((size_t)(b * 16 + h)) * 16384 +
                 (d0 + r) * 1024 + ns] = f2bf(v[r]);
        }
      } else if (MODE == MODE_Y_RES) {
        size_t idx = (size_t)mrow * N + ncb;
        union { u16 u[4]; uint2 x; } rv, ov;
        rv.x = *(const uint2*)(resp + idx);
        #pragma unroll
        for (int r = 0; r < 4; ++r) {
          float rr = bf2f(rv.u[r]);
          if (RESN == 2) rr = rr * scj[r] + sfj[r];
          float y = v[r] + rr;
          ov.u[r] = f2bf(y);
          if (STATS) { sjr[r] += y; qjr[r] += y * y; }
        }
        *(uint2*)(outB + idx) = ov.x;
      } else { // MODE_GLU: (v[0],v[1]) and (v[2],v[3]) are (x,gate) pairs
        union { u16 u[2]; unsigned x; } o;
        float g0 = v[1] / (1.f + __expf(-v[1]));
        float g1 = v[3] / (1.f + __expf(-v[3]));
        o.u[0] = f2bf(v[0] * g0);
        o.u[1] = f2bf(v[2] * g1);
        *(unsigned*)(outB + (size_t)mrow * 512 + (ncb >> 1)) = o.x;
      }
    }
    if (STATS) {
      #pragma unroll
      for (int r = 0; r < 4; ++r) {
        float s = sjr[r], q = qjr[r];
        s += __shfl_xor(s, 1); s += __shfl_xor(s, 2);
        s += __shfl_xor(s, 4); s += __shfl_xor(s, 8);
        q += __shfl_xor(q, 1); q += __shfl_xor(q, 2);
        q += __shfl_xor(q, 4); q += __shfl_xor(q, 8);
        if (fr == 0) {
          atomicAdd(&ssum[bIdx * 256 + ncb + r], s);
          atomicAdd(&ssq[bIdx * 256 + ncb + r], q);
        }
      }
    }
  }
}

// ---------------------------------------------------------------------------
// Attention v5 (unchanged from r10): in-register P, async K staging,
// d-major V, XCD swizzle.
// ---------------------------------------------------------------------------
#define SCALE_L2 0.360673760222241f   /* (1/sqrt(16)) * log2(e) */

__launch_bounds__(512, 4)
__global__ void attn_kernel(const u16* __restrict__ Q, const u16* __restrict__ Kg,
                            const u16* __restrict__ Vg, u16* __restrict__ attn)
{
  __shared__ u16 Ks[2][128 * 16];
  __shared__ u16 Vt[2][16 * 136];
  const int t = threadIdx.x;
  const int bh = blockIdx.x & 255;
  const int qg = blockIdx.x >> 8;
  const int b = bh >> 4, h = bh & 15;
  const size_t base = (size_t)bh * 16384;
  const int w = t >> 6, lane = t & 63;
  const int fr = lane & 15, fg = lane >> 4;
  const int q0 = qg * 128 + w * 16;
  const f32x4 zero4 = (f32x4){0.f, 0.f, 0.f, 0.f};
  const bool isK = t < 256;

  const int si = lane >> 1;
  const int halfo = (lane & 1) * 8;
  const int keyloc = (si < 16) ? (2 * si) : (2 * (si - 16) + 1);
  const int unit = t - 256;
  const int vd = unit >> 4, voct = unit & 15;

  bf16x8 qf = {};
  if (fg < 2) {
    union { u16 u[8]; uint4 v; bf16x8 f; } qt;
    qt.v = *(const uint4*)(Q + base + (size_t)(q0 + fr) * 16 + fg * 8);
    #pragma unroll
    for (int j = 0; j < 8; ++j) qt.u[j] = f2bf(bf2f(qt.u[j]) * SCALE_L2);
    qf = qt.f;
  }

  if (isK) {
    gll16(Kg + base + (size_t)(32 * w + keyloc) * 16 + halfo, &Ks[0][0] + w * 512);
  } else {
    uint4 v = *(const uint4*)(Vg + base + vd * 1024 + voct * 8);
    *(uint4*)(&Vt[0][vd * 136 + voct * 8]) = v;
  }
  __syncthreads();

  f32x4 acco = zero4;
  float lsum = 0.f;

  for (int c = 0; c < 8; ++c) {
    uint4 nxt;
    if (c < 7) {
      if (isK)
        gll16(Kg + base + (size_t)((c + 1) * 128 + 32 * w + keyloc) * 16 + halfo,
              &Ks[(c + 1) & 1][0] + w * 512);
      else
        nxt = *(const uint4*)(Vg + base + vd * 1024 + (c + 1) * 128 + voct * 8);
    }
    const u16* KsC = Ks[c & 1];
    const u16* VtC = Vt[c & 1];
    #pragma unroll
    for (int sub = 0; sub < 4; ++sub) {
      const int kb = sub * 32;
      bf16x8 kf0 = {}, kf1 = {};
      if (fg < 2) {
        kf0 = *(const bf16x8*)(KsC + (kb + fr) * 16 + fg * 8);
        kf1 = *(const bf16x8*)(KsC + (kb + 16 + fr) * 16 + fg * 8);
      }
      f32x4 s0 = __builtin_amdgcn_mfma_f32_16x16x32_bf16(kf0, qf, zero4, 0, 0, 0);
      f32x4 s1 = __builtin_amdgcn_mfma_f32_16x16x32_bf16(kf1, qf, zero4, 0, 0, 0);
      union { unsigned d[4]; bf16x8 f; } pf;
      #pragma unroll
      for (int r = 0; r < 4; ++r) {
        float p0 = fexp2(s0[r]);
        float p1 = fexp2(s1[r]);
        lsum += p0 + p1;
        pf.d[r] = __builtin_amdgcn_perm(__float_as_uint(p1), __float_as_uint(p0), 0x07060302u);
      }
      bf16x8 vf = *(const bf16x8*)(VtC + fr * 136 + kb + fg * 8);
      acco = __builtin_amdgcn_mfma_f32_16x16x32_bf16(vf, pf.f, acco, 0, 0, 0);
    }
    if (c < 7 && !isK)
      *(uint4*)(&Vt[(c + 1) & 1][vd * 136 + voct * 8]) = nxt;
    __syncthreads();
  }

  lsum += __shfl_xor(lsum, 16);
  lsum += __shfl_xor(lsum, 32);
  float inv = 1.f / lsum;
  union { u16 u[4]; uint2 v; } ov;
  #pragma unroll
  for (int r = 0; r < 4; ++r) ov.u[r] = f2bf(acco[r] * inv);
  *(uint2*)(attn + ((size_t)(b * 1024 + q0 + fr)) * 256 + h * 16 + fg * 4) = ov.v;
}

// ---------------------------------------------------------------------------
// Final instance-norm apply -> fp32 output.
// ---------------------------------------------------------------------------
__global__ void apply_kernel(const u16* __restrict__ y, const float* __restrict__ ssum,
                             const float* __restrict__ ssq, const float* __restrict__ gamma,
                             const float* __restrict__ beta, float* __restrict__ outp)
{
  int idx = (blockIdx.x * 256 + threadIdx.x) * 4;
  int e = idx & 255;
  int b = idx >> 18;
  union { u16 u[4]; uint2 v; } in;
  in.v = *(const uint2*)(y + idx);
  float ov[4];
  const float inv = 1.f / 1024.f;
  #pragma unroll
  for (int j = 0; j < 4; ++j) {
    int ej = e + j;
    float mean = ssum[b * 256 + ej] * inv;
    float var = ssq[b * 256 + ej] * inv - mean * mean;
    float rstd = rsqrtf(var + 1e-5f);
    ov[j] = (bf2f(in.u[j]) - mean) * rstd * gamma[ej] + beta[ej];
  }
  *(float4*)(outp + idx) = make_float4(ov[0], ov[1], ov[2], ov[3]);
}

// ---------------------------------------------------------------------------
extern "C" void kernel_launch(void* const* d_in, const int* in_sizes, int n_in,
                              void* d_out, int out_size, void* d_ws, size_t ws_size,
                              hipStream_t stream)
{
  const float* x      = (const float*)d_in[0];
  const float* Wq     = (const float*)d_in[1];
  const float* Wk     = (const float*)d_in[2];
  const float* Wv     = (const float*)d_in[3];
  const float* Wo     = (const float*)d_in[4];
  const float* bo     = (const float*)d_in[5];
  const float* gamma1 = (const float*)d_in[6];
  const float* beta1  = (const float*)d_in[7];
  const float* gamma2 = (const float*)d_in[8];
  const float* beta2  = (const float*)d_in[9];
  const float* W1     = (const float*)d_in[10];
  const float* b1     = (const float*)d_in[11];
  const float* W2     = (const float*)d_in[12];
  const float* b2     = (const float*)d_in[13];

  // Workspace (49.3 MB peak, lifetime-aliased) — same layout as r7/r9/r10:
  char* ws = (char*)d_ws;
  u16*   WQKVT = (u16*)(ws + 0);
  u16*   WOT   = (u16*)(ws + 393216);
  u16*   W1T   = (u16*)(ws + 524288);
  u16*   W2T   = (u16*)(ws + 1048576);
  float* SS    = (float*)(ws + 1310720);
  float* SSUM1 = SS;
  float* SSQ1  = SS + 4096;
  float* SSUM2 = SS + 8192;
  float* SSQ2  = SS + 12288;
  u16*   xb    = (u16*)(ws + 1376256);
  u16*   Qb    = (u16*)(ws + 9764864);
  u16*   ATTN  = (u16*)(ws + 34930688);
  u16*   Y1    = (u16*)(ws + 9764864);
  u16*   G     = (u16*)(ws + 18153472);
  u16*   Y2    = (u16*)(ws + 34930688);

  prep_kernel<<<2688, 256, 0, stream>>>(x, xb, Wq, Wk, Wv, Wo, W1, W2,
                                        WQKVT, WOT, W1T, W2T, SS);

  gemm_kernel<MODE_QKV, 128, 0, 0, 0><<<dim3(128, 6), 256, 0, stream>>>(
      xb, WQKVT, 16384, 768, 256, nullptr, nullptr, Qb,
      nullptr, nullptr, nullptr, nullptr, nullptr, nullptr);

  attn_kernel<<<2048, 512, 0, stream>>>(Qb, Qb + 4194304, Qb + 8388608, ATTN);

  gemm_kernel<MODE_Y_RES, 64, 1, 1, 0><<<dim3(128, 4), 256, 0, stream>>>(
      ATTN, WOT, 16384, 256, 256, bo, xb, Y1,
      SSUM1, SSQ1, nullptr, nullptr, nullptr, nullptr);

  gemm_kernel<MODE_GLU, 128, 0, 0, 1><<<dim3(128, 8), 256, 0, stream>>>(
      Y1, W1T, 16384, 1024, 256, b1, nullptr, G,
      nullptr, nullptr, SSUM1, SSQ1, gamma1, beta1);

  gemm_kernel<MODE_Y_RES, 64, 2, 1, 0><<<dim3(128, 4), 256, 0, stream>>>(
      G, W2T, 16384, 256, 512, b2, Y1, Y2,
      SSUM2, SSQ2, SSUM1, SSQ1, gamma1, beta1);

  apply_kernel<<<4096, 256, 0, stream>>>(Y2, SSUM2, SSQ2, gamma2, beta2, (float*)d_out);
}